// Round 7
// baseline (699.166 us; speedup 1.0000x reference)
//
#include <hip/hip_runtime.h>

#define T_STEPS 512
#define HID 64

typedef short bf16x8 __attribute__((ext_vector_type(8)));
typedef float f32x4 __attribute__((ext_vector_type(4)));

__device__ __forceinline__ float sigm(float x) {
  return __builtin_amdgcn_rcpf(1.f + __expf(-x));
}
__device__ __forceinline__ float tanh_fast(float x) {
  return 1.f - 2.f * __builtin_amdgcn_rcpf(__expf(2.f * x) + 1.f);
}

// split fp32 -> bf16 hi (chop) + bf16 lo (chop of exact residual)
__device__ __forceinline__ void split1(float v, short* hi, short* lo) {
  unsigned u = __float_as_uint(v);
  float r = v - __uint_as_float(u & 0xffff0000u);   // exact in fp32
  *hi = (short)(u >> 16);
  *lo = (short)(__float_as_uint(r) >> 16);
}

__device__ __forceinline__ void split8(const float* __restrict__ p, bf16x8& hi, bf16x8& lo) {
  float v[8];
  *(float4*)&v[0] = *(const float4*)p;
  *(float4*)&v[4] = *(const float4*)(p + 4);
  #pragma unroll
  for (int i = 0; i < 8; ++i) {
    unsigned u = __float_as_uint(v[i]);
    float r = v[i] - __uint_as_float(u & 0xffff0000u);
    hi[i] = (short)(u >> 16);
    lo[i] = (short)(__float_as_uint(r) >> 16);
  }
}

#define MM(acc, A, B) acc = __builtin_amdgcn_mfma_f32_16x16x32_bf16((A), (B), (acc), 0, 0, 0)

// K-concat 6-chunk accumulation: Wh*vh (2 chunks) + Wh*vl + Wl*vh
#define GATE6(acc, IH0, IH1, IL0, IL1, NM) do { \
    MM(acc, IH0, NM##h0); MM(acc, IH1, NM##h1); \
    MM(acc, IL0, NM##h0); MM(acc, IL1, NM##h1); \
    MM(acc, IH0, NM##l0); MM(acc, IH1, NM##l1); } while (0)

#define WFRAG(NM, Wp, goff) \
  bf16x8 NM##h0, NM##l0, NM##h1, NM##l1; \
  split8((Wp) + (goff) * (64 * HID) + wrowoff, NM##h0, NM##l0); \
  split8((Wp) + (goff) * (64 * HID) + wrowoff + 32, NM##h1, NM##l1)

// wait until min(ws[base..base+3]) >= thresh (acquire)
__device__ __forceinline__ void waitge(int* ws, int base, int thresh) {
  for (;;) {
    int m0 = __atomic_load_n(ws + base,     __ATOMIC_ACQUIRE);
    int m1 = __atomic_load_n(ws + base + 1, __ATOMIC_ACQUIRE);
    int m2 = __atomic_load_n(ws + base + 2, __ATOMIC_ACQUIRE);
    int m3 = __atomic_load_n(ws + base + 3, __ATOMIC_ACQUIRE);
    if (m0 >= thresh && m1 >= thresh && m2 >= thresh && m3 >= thresh) return;
    __builtin_amdgcn_s_sleep(1);
  }
}

// Grid 256 x WG 512 (8 waves, 2/SIMD). Waves 0-3: layer 0; waves 4-7: layer 1.
// NO __syncthreads in the main loop: per-wave step flags (acquire/release) +
// ring buffers (xs/hA depth 4, hB depth 2) let the two waves per SIMD run out
// of phase, so one wave's epilogue/LDS latency hides under the other's MFMAs.
// Flag protocol: L0@t needs minL0>=t-1 (state hA(t-1), xs(t)) and minL1>=t-4
// (hA/xs slot reuse). L1@t needs minL1>=t-1 (state hB(t-1), checked first;
// 18 state MFMAs issue while possibly waiting) then minL0>=t (input hA(t)).
__global__ __launch_bounds__(512, 2) void gru_mfma(
    const float* __restrict__ x,
    const float* __restrict__ Wih0, const float* __restrict__ Whh0,
    const float* __restrict__ bih0, const float* __restrict__ bhh0,
    const float* __restrict__ Wih1, const float* __restrict__ Whh1,
    const float* __restrict__ bih1, const float* __restrict__ bhh1,
    const float* __restrict__ W1, const float* __restrict__ b1,
    const float* __restrict__ W2, const float* __restrict__ b2,
    float* __restrict__ out)
{
  const int tid   = threadIdx.x;
  const int lane  = tid & 63;
  const int wv8   = tid >> 6;       // 0..7
  const int layer = wv8 >> 2;       // 0 or 1
  const int ws    = wv8 & 3;        // j-slice within layer
  const int nloc  = lane & 15;
  const int quad  = lane >> 4;
  const int b0    = blockIdx.x << 2;

  __shared__ __align__(16) short xsH[4][1024], xsL[4][1024];
  __shared__ __align__(16) short hAH[4][1024], hAL[4][1024];
  __shared__ __align__(16) short hBH[2][1024], hBL[2][1024];
  __shared__ int wstep[8];
  __shared__ float hfin[256];
  __shared__ float msf[128];

  // ---- this wave's layer weights only (layouts verified R4-R6) ----
  const float* Wi = layer ? Wih1 : Wih0;
  const float* Wh = layer ? Whh1 : Whh0;
  const float* bi = layer ? bih1 : bih0;
  const float* bh = layer ? bhh1 : bhh0;

  const int wrowoff = (16 * ws + nloc) * HID + 8 * quad;
  WFRAG(wir, Wi, 0); WFRAG(wiz, Wi, 1); WFRAG(win, Wi, 2);
  WFRAG(whr, Wh, 0); WFRAG(whz, Wh, 1); WFRAG(whn, Wh, 2);

  const int jg = 16 * ws + nloc;
  const float b_r = bi[jg] + bh[jg];
  const float b_z = bi[jg + 64] + bh[jg + 64];
  const float b_i = bi[jg + 128];
  const float b_h = bh[jg + 128];

  // loop-invariant LDS indices (shorts) — XOR-swizzled layout (conflict-free, R5)
  const int ra0 = nloc * 64 + (((quad    ) ^ (nloc & 7)) << 3);
  const int ra1 = nloc * 64 + (((quad + 4) ^ (nloc & 7)) << 3);
  const int hwr = quad * 256 + (((jg >> 3) ^ ((quad & 1) << 2)) << 3) + (jg & 7);

  // x stager: L0 threads (tid<256), batch = ws, channel = lane
  const float* xptr = x + ((size_t)(b0 + ws) * HID + lane) * T_STEPS;
  const int xwr = ws * 256 + (((lane >> 3) ^ ((ws & 1) << 2)) << 3) + (lane & 7);

  for (int i = tid; i < 4096; i += 512) {
    (&xsH[0][0])[i] = 0; (&xsL[0][0])[i] = 0;
    (&hAH[0][0])[i] = 0; (&hAL[0][0])[i] = 0;
  }
  for (int i = tid; i < 2048; i += 512) {
    (&hBH[0][0])[i] = 0; (&hBL[0][0])[i] = 0;
  }
  if (tid < 8) wstep[tid] = -1;
  __syncthreads();
  if (layer == 0) {                      // stage xs(0)
    short h, l; split1(xptr[0], &h, &l);
    xsH[0][xwr] = h; xsL[0][xwr] = l;
  }
  __syncthreads();

  float hp = 0.f;                        // lane's h[batch=quad][j=jg]
  float xcur = (layer == 0) ? xptr[1] : 0.f;   // x(t+1) value at step t

  #pragma unroll 1
  for (int t = 0; t < T_STEPS; ++t) {
    const short *stH, *stL;
    if (layer == 0) {
      waitge(wstep, 0, t - 1);
      waitge(wstep, 4, t - 4);
      stH = hAH[(t - 1) & 3]; stL = hAL[(t - 1) & 3];
    } else {
      waitge(wstep, 4, t - 1);
      stH = hBH[(t - 1) & 1]; stL = hBL[(t - 1) & 1];
    }
    const bf16x8 SH0 = *(const bf16x8*)&stH[ra0], SH1 = *(const bf16x8*)&stH[ra1];
    const bf16x8 SL0 = *(const bf16x8*)&stL[ra0], SL1 = *(const bf16x8*)&stL[ra1];

    f32x4 aR = {0,0,0,0}, aZ = {0,0,0,0}, aI = {0,0,0,0}, aH = {0,0,0,0};
    GATE6(aR, SH0, SH1, SL0, SL1, whr);
    GATE6(aZ, SH0, SH1, SL0, SL1, whz);
    GATE6(aH, SH0, SH1, SL0, SL1, whn);

    if (layer == 1) waitge(wstep, 0, t);   // input hA(t)
    const short* inH = layer ? hAH[t & 3] : xsH[t & 3];
    const short* inL = layer ? hAL[t & 3] : xsL[t & 3];
    const bf16x8 IH0 = *(const bf16x8*)&inH[ra0], IH1 = *(const bf16x8*)&inH[ra1];
    const bf16x8 IL0 = *(const bf16x8*)&inL[ra0], IL1 = *(const bf16x8*)&inL[ra1];
    GATE6(aR, IH0, IH1, IL0, IL1, wir);
    GATE6(aZ, IH0, IH1, IL0, IL1, wiz);
    GATE6(aI, IH0, IH1, IL0, IL1, win);

    {
      const float r = sigm(aR[0] + b_r);
      const float z = sigm(aZ[0] + b_z);
      const float n = tanh_fast((aI[0] + b_i) + r * (aH[0] + b_h));
      hp = n + z * (hp - n);
      short h, l; split1(hp, &h, &l);
      if (layer == 0) { hAH[t & 3][hwr] = h; hAL[t & 3][hwr] = l; }
      else            { hBH[t & 1][hwr] = h; hBL[t & 1][hwr] = l; }
    }
    if (layer == 0) {                    // stage xs(t+1)
      short h, l; split1(xcur, &h, &l);
      xsH[(t + 1) & 3][xwr] = h; xsL[(t + 1) & 3][xwr] = l;
    }
    if (lane == 0) __atomic_store_n(&wstep[wv8], t, __ATOMIC_RELEASE);
    if (layer == 0) xcur = (t + 2 < T_STEPS) ? xptr[t + 2] : 0.f;  // prefetch after flag
  }

  if (layer == 1) hfin[quad * 64 + jg] = hp;   // hB(T-1)
  __syncthreads();

  // ---- classifier ----
  if (tid < 128) {
    const int bb = tid >> 5, u = tid & 31;
    float acc = b1[u];
    const float* w1r = W1 + u * HID;
    #pragma unroll
    for (int k = 0; k < 64; ++k)
      acc = fmaf(w1r[k], hfin[bb * 64 + k], acc);
    msf[(bb << 5) + u] = fmaxf(acc, 0.f);
  }
  __syncthreads();
  if (tid < 16) {
    const int bb = tid >> 2, c = tid & 3;
    float acc = b2[c];
    const float* w2r = W2 + (c << 5);
    #pragma unroll
    for (int u = 0; u < 32; ++u)
      acc = fmaf(w2r[u], msf[(bb << 5) + u], acc);
    out[(size_t)(b0 + bb) * 4 + c] = acc;
  }
}

extern "C" void kernel_launch(void* const* d_in, const int* in_sizes, int n_in,
                              void* d_out, int out_size, void* d_ws, size_t ws_size,
                              hipStream_t stream) {
  const float* x    = (const float*)d_in[0];
  const float* Wih0 = (const float*)d_in[1];
  const float* Whh0 = (const float*)d_in[2];
  const float* bih0 = (const float*)d_in[3];
  const float* bhh0 = (const float*)d_in[4];
  const float* Wih1 = (const float*)d_in[5];
  const float* Whh1 = (const float*)d_in[6];
  const float* bih1 = (const float*)d_in[7];
  const float* bhh1 = (const float*)d_in[8];
  const float* W1   = (const float*)d_in[9];
  const float* b1   = (const float*)d_in[10];
  const float* W2   = (const float*)d_in[11];
  const float* b2   = (const float*)d_in[12];
  float* out = (float*)d_out;

  hipLaunchKernelGGL(gru_mfma, dim3(256), dim3(512), 0, stream,
                     x, Wih0, Whh0, bih0, bhh0, Wih1, Whh1, bih1, bhh1,
                     W1, b1, W2, b2, out);
}

// Round 8
// 615.285 us; speedup vs baseline: 1.1363x; 1.1363x over previous
//
#include <hip/hip_runtime.h>

#define T_STEPS 512
#define HID 64

typedef short bf16x8 __attribute__((ext_vector_type(8)));
typedef float f32x4 __attribute__((ext_vector_type(4)));

__device__ __forceinline__ float sigm(float x) {
  return __builtin_amdgcn_rcpf(1.f + __expf(-x));
}
__device__ __forceinline__ float tanh_fast(float x) {
  return 1.f - 2.f * __builtin_amdgcn_rcpf(__expf(2.f * x) + 1.f);
}

// split fp32 -> bf16 hi (chop) + bf16 lo (chop of exact residual)
__device__ __forceinline__ void split1(float v, short* hi, short* lo) {
  unsigned u = __float_as_uint(v);
  float r = v - __uint_as_float(u & 0xffff0000u);   // exact in fp32
  *hi = (short)(u >> 16);
  *lo = (short)(__float_as_uint(r) >> 16);
}

__device__ __forceinline__ void split8(const float* __restrict__ p, bf16x8& hi, bf16x8& lo) {
  float v[8];
  *(float4*)&v[0] = *(const float4*)p;
  *(float4*)&v[4] = *(const float4*)(p + 4);
  #pragma unroll
  for (int i = 0; i < 8; ++i) {
    unsigned u = __float_as_uint(v[i]);
    float r = v[i] - __uint_as_float(u & 0xffff0000u);
    hi[i] = (short)(u >> 16);
    lo[i] = (short)(__float_as_uint(r) >> 16);
  }
}

#define MM(acc, A, B) acc = __builtin_amdgcn_mfma_f32_16x16x32_bf16((A), (B), (acc), 0, 0, 0)

// K-concat 6-chunk accumulation: Wh*vh (2 chunks) + Wh*vl + Wl*vh
#define GATE6(acc, IH0, IH1, IL0, IL1, NM) do { \
    MM(acc, IH0, NM##h0); MM(acc, IH1, NM##h1); \
    MM(acc, IL0, NM##h0); MM(acc, IL1, NM##h1); \
    MM(acc, IH0, NM##l0); MM(acc, IH1, NM##l1); } while (0)

#define WFRAG(NM, Wp, goff) \
  bf16x8 NM##h0, NM##l0, NM##h1, NM##l1; \
  split8((Wp) + (goff) * (64 * HID) + wrowoff, NM##h0, NM##l0); \
  split8((Wp) + (goff) * (64 * HID) + wrowoff + 32, NM##h1, NM##l1)

// Grid 256 x WG 256 (4 waves, 1/SIMD). Wave wv owns j-slice [16wv,16wv+16) for
// BOTH layers (192 weight VGPRs; fine at 1 wave/SIMD = 512-reg budget).
// Single-barrier pipelined body(t): computes L1(t) then L0(t+1).
//   after barrier: read IA=hA(t), SB=hB(t-1);
//   L0x(t+1) 18 mfma (xs frags pre-read -> covers read latency);
//   L1i 18 (IA); L1h 18 (SB); L0h(t+1) 18 (state = IA, no copy);
//   L1 epilogue (interleaves under L0h) -> write hB(t);
//   L0 epilogue -> write hA(t+1); xs refill (every 4 steps); pre-read XS(t+2); barrier.
// LDS XOR-swizzled layouts verified R5 (conflict-free).
__global__ __launch_bounds__(256, 1) void gru_mfma(
    const float* __restrict__ x,
    const float* __restrict__ Wih0, const float* __restrict__ Whh0,
    const float* __restrict__ bih0, const float* __restrict__ bhh0,
    const float* __restrict__ Wih1, const float* __restrict__ Whh1,
    const float* __restrict__ bih1, const float* __restrict__ bhh1,
    const float* __restrict__ W1, const float* __restrict__ b1,
    const float* __restrict__ W2, const float* __restrict__ b2,
    float* __restrict__ out)
{
  const int tid  = threadIdx.x;
  const int lane = tid & 63;
  const int wv   = tid >> 6;        // 0..3
  const int nloc = lane & 15;
  const int quad = lane >> 4;
  const int b0   = blockIdx.x << 2;

  __shared__ __align__(16) short xsH[8][1024], xsL[8][1024];
  __shared__ __align__(16) short hAH[2][1024], hAL[2][1024];
  __shared__ __align__(16) short hBH[2][1024], hBL[2][1024];
  __shared__ float hfin[256];
  __shared__ float msf[128];

  // ---- weights, both layers (layouts verified R4-R7) ----
  const int wrowoff = (16 * wv + nloc) * HID + 8 * quad;
  WFRAG(i0r, Wih0, 0); WFRAG(i0z, Wih0, 1); WFRAG(i0n, Wih0, 2);
  WFRAG(h0r, Whh0, 0); WFRAG(h0z, Whh0, 1); WFRAG(h0n, Whh0, 2);
  WFRAG(i1r, Wih1, 0); WFRAG(i1z, Wih1, 1); WFRAG(i1n, Wih1, 2);
  WFRAG(h1r, Whh1, 0); WFRAG(h1z, Whh1, 1); WFRAG(h1n, Whh1, 2);

  const int jg = 16 * wv + nloc;
  const float bA_r = bih0[jg] + bhh0[jg];
  const float bA_z = bih0[jg + 64] + bhh0[jg + 64];
  const float bA_i = bih0[jg + 128], bA_h = bhh0[jg + 128];
  const float bB_r = bih1[jg] + bhh1[jg];
  const float bB_z = bih1[jg + 64] + bhh1[jg + 64];
  const float bB_i = bih1[jg + 128], bB_h = bhh1[jg + 128];

  // loop-invariant LDS indices (shorts) — XOR-swizzled (conflict-free, R5)
  const int ra0 = nloc * 64 + (((quad    ) ^ (nloc & 7)) << 3);
  const int ra1 = nloc * 64 + (((quad + 4) ^ (nloc & 7)) << 3);
  const int hwr = quad * 256 + (((jg >> 3) ^ ((quad & 1) << 2)) << 3) + (jg & 7);

  // x stager: thread (batch=wv, channel=lane)
  const float* xptr = x + ((size_t)(b0 + wv) * HID + lane) * T_STEPS;
  const int xwr = wv * 256 + (((lane >> 3) ^ ((wv & 1) << 2)) << 3) + (lane & 7);

  for (int i = tid; i < 1024; i += 256) {
    hAH[0][i] = 0; hAL[0][i] = 0; hAH[1][i] = 0; hAL[1][i] = 0;
    hBH[0][i] = 0; hBL[0][i] = 0; hBH[1][i] = 0; hBL[1][i] = 0;
  }
  {   // stage xs(0..3)
    const float4 v = *(const float4*)xptr;
    const float vv[4] = {v.x, v.y, v.z, v.w};
    #pragma unroll
    for (int s = 0; s < 4; ++s) {
      short h, l; split1(vv[s], &h, &l);
      xsH[s][xwr] = h; xsL[s][xwr] = l;
    }
  }
  __syncthreads();

  // pre-read XS(0) and XS(1)
  bf16x8 P0H0 = *(const bf16x8*)&xsH[0][ra0], P0H1 = *(const bf16x8*)&xsH[0][ra1];
  bf16x8 P0L0 = *(const bf16x8*)&xsL[0][ra0], P0L1 = *(const bf16x8*)&xsL[0][ra1];
  bf16x8 XH0 = *(const bf16x8*)&xsH[1][ra0], XH1 = *(const bf16x8*)&xsH[1][ra1];
  bf16x8 XL0 = *(const bf16x8*)&xsL[1][ra0], XL1 = *(const bf16x8*)&xsL[1][ra1];

  float hpa, hpb = 0.f;
  {   // prologue: L0(0) with h(-1)=0 -> x-gates only
    f32x4 bR = {0,0,0,0}, bZ = {0,0,0,0}, bI = {0,0,0,0};
    GATE6(bR, P0H0, P0H1, P0L0, P0L1, i0r);
    GATE6(bZ, P0H0, P0H1, P0L0, P0L1, i0z);
    GATE6(bI, P0H0, P0H1, P0L0, P0L1, i0n);
    const float r = sigm(bR[0] + bA_r);
    const float z = sigm(bZ[0] + bA_z);
    const float n = tanh_fast((bI[0] + bA_i) + r * bA_h);
    hpa = n - z * n;
    short h, l; split1(hpa, &h, &l);
    hAH[0][hwr] = h; hAL[0][hwr] = l;
  }
  __syncthreads();

  #pragma unroll 1
  for (int t = 0; t < T_STEPS; ++t) {
    const int pa = t & 1, pb = pa ^ 1;
    // reads: IA = hA(t) [slot pa], SB = hB(t-1) [slot pb]
    const bf16x8 IAH0 = *(const bf16x8*)&hAH[pa][ra0], IAH1 = *(const bf16x8*)&hAH[pa][ra1];
    const bf16x8 IAL0 = *(const bf16x8*)&hAL[pa][ra0], IAL1 = *(const bf16x8*)&hAL[pa][ra1];
    const bf16x8 SBH0 = *(const bf16x8*)&hBH[pb][ra0], SBH1 = *(const bf16x8*)&hBH[pb][ra1];
    const bf16x8 SBL0 = *(const bf16x8*)&hBL[pb][ra0], SBL1 = *(const bf16x8*)&hBL[pb][ra1];

    // L0(t+1) x-gates — operands in regs, covers the read latency above
    f32x4 bR = {0,0,0,0}, bZ = {0,0,0,0}, bI = {0,0,0,0}, bH = {0,0,0,0};
    GATE6(bR, XH0, XH1, XL0, XL1, i0r);
    GATE6(bZ, XH0, XH1, XL0, XL1, i0z);
    GATE6(bI, XH0, XH1, XL0, XL1, i0n);

    // L1(t): input gates (IA) then hidden gates (SB)
    f32x4 cR = {0,0,0,0}, cZ = {0,0,0,0}, cI = {0,0,0,0}, cH = {0,0,0,0};
    GATE6(cR, IAH0, IAH1, IAL0, IAL1, i1r);
    GATE6(cZ, IAH0, IAH1, IAL0, IAL1, i1z);
    GATE6(cI, IAH0, IAH1, IAL0, IAL1, i1n);
    GATE6(cR, SBH0, SBH1, SBL0, SBL1, h1r);
    GATE6(cZ, SBH0, SBH1, SBL0, SBL1, h1z);
    GATE6(cH, SBH0, SBH1, SBL0, SBL1, h1n);

    // L0(t+1) hidden gates — state = IA (hA(t)), no copy needed
    GATE6(bR, IAH0, IAH1, IAL0, IAL1, h0r);
    GATE6(bZ, IAH0, IAH1, IAL0, IAL1, h0z);
    GATE6(bH, IAH0, IAH1, IAL0, IAL1, h0n);

    // L1 epilogue (interleaves under L0h burst) -> hB(t) slot pa
    {
      const float r = sigm(cR[0] + bB_r);
      const float z = sigm(cZ[0] + bB_z);
      const float n = tanh_fast((cI[0] + bB_i) + r * (cH[0] + bB_h));
      hpb = n + z * (hpb - n);
      short h, l; split1(hpb, &h, &l);
      hBH[pa][hwr] = h; hBL[pa][hwr] = l;
    }
    // L0 epilogue -> hA(t+1) slot pb
    {
      const float r = sigm(bR[0] + bA_r);
      const float z = sigm(bZ[0] + bA_z);
      const float n = tanh_fast((bI[0] + bA_i) + r * (bH[0] + bA_h));
      hpa = n + z * (hpa - n);
      short h, l; split1(hpa, &h, &l);
      hAH[pb][hwr] = h; hAL[pb][hwr] = l;
    }
    // xs ring refill: every 4 steps stage x(t+4..t+7)
    if ((t & 3) == 0 && t < T_STEPS - 4) {
      const float4 v = *(const float4*)(xptr + t + 4);
      const float vv[4] = {v.x, v.y, v.z, v.w};
      #pragma unroll
      for (int s = 0; s < 4; ++s) {
        short h, l; split1(vv[s], &h, &l);
        xsH[(t + 4 + s) & 7][xwr] = h; xsL[(t + 4 + s) & 7][xwr] = l;
      }
    }
    // pre-read XS(t+2) (slot never touched by this body's refill)
    {
      const int sx = (t + 2) & 7;
      XH0 = *(const bf16x8*)&xsH[sx][ra0]; XH1 = *(const bf16x8*)&xsH[sx][ra1];
      XL0 = *(const bf16x8*)&xsL[sx][ra0]; XL1 = *(const bf16x8*)&xsL[sx][ra1];
    }
    __syncthreads();
  }

  hfin[quad * 64 + jg] = hpb;   // hB(T-1)
  __syncthreads();

  // ---- classifier ----
  if (tid < 128) {
    const int bb = tid >> 5, u = tid & 31;
    float acc = b1[u];
    const float* w1r = W1 + u * HID;
    #pragma unroll
    for (int k = 0; k < 64; ++k)
      acc = fmaf(w1r[k], hfin[bb * 64 + k], acc);
    msf[(bb << 5) + u] = fmaxf(acc, 0.f);
  }
  __syncthreads();
  if (tid < 16) {
    const int bb = tid >> 2, c = tid & 3;
    float acc = b2[c];
    const float* w2r = W2 + (c << 5);
    #pragma unroll
    for (int u = 0; u < 32; ++u)
      acc = fmaf(w2r[u], msf[(bb << 5) + u], acc);
    out[(size_t)(b0 + bb) * 4 + c] = acc;
  }
}

extern "C" void kernel_launch(void* const* d_in, const int* in_sizes, int n_in,
                              void* d_out, int out_size, void* d_ws, size_t ws_size,
                              hipStream_t stream) {
  const float* x    = (const float*)d_in[0];
  const float* Wih0 = (const float*)d_in[1];
  const float* Whh0 = (const float*)d_in[2];
  const float* bih0 = (const float*)d_in[3];
  const float* bhh0 = (const float*)d_in[4];
  const float* Wih1 = (const float*)d_in[5];
  const float* Whh1 = (const float*)d_in[6];
  const float* bih1 = (const float*)d_in[7];
  const float* bhh1 = (const float*)d_in[8];
  const float* W1   = (const float*)d_in[9];
  const float* b1   = (const float*)d_in[10];
  const float* W2   = (const float*)d_in[11];
  const float* b2   = (const float*)d_in[12];
  float* out = (float*)d_out;

  hipLaunchKernelGGL(gru_mfma, dim3(256), dim3(256), 0, stream,
                     x, Wih0, Whh0, bih0, bhh0, Wih1, Whh1, bih1, bhh1,
                     W1, b1, W2, b2, out);
}